// Round 5
// baseline (191.082 us; speedup 1.0000x reference)
//
#include <hip/hip_runtime.h>
#include <stdint.h>
#include <stddef.h>

typedef __attribute__((ext_vector_type(4)))  float  f32x4;
typedef __attribute__((ext_vector_type(16))) float  f32x16;
typedef __attribute__((ext_vector_type(8)))  short  s16x8;
typedef __attribute__((ext_vector_type(4)))  float  float4v;
typedef __attribute__((ext_vector_type(4)))  unsigned short u16x4;
typedef __attribute__((ext_vector_type(4)))  unsigned int   u32x4;

#define DIM    1024
#define HEADS  16
#define HD     64
#define SEQ    2048
#define BATCH  2
#define TOKENS (BATCH * SEQ)   // 4096

// 0.125 (1/sqrt(64)) * log2(e): folded into Q so softmax uses exp2 directly
#define QSCALE 0.18033688011112042f

// ---------- helpers ----------
__device__ __forceinline__ unsigned short f2bf(float f) {
  union { float f; uint32_t u; } x; x.f = f;
  uint32_t r = x.u + 0x7fffu + ((x.u >> 16) & 1u);   // RNE
  return (unsigned short)(r >> 16);
}

__device__ __forceinline__ float fast_exp2(float x) {
#if __has_builtin(__builtin_amdgcn_exp2f)
  return __builtin_amdgcn_exp2f(x);
#else
  return exp2f(x);
#endif
}

// pack high-16s of two fp32 into one dword: (hi & 0xffff0000) | (lo >> 16)
__device__ __forceinline__ uint32_t pack_bf16_trunc(uint32_t lo, uint32_t hi) {
#if __has_builtin(__builtin_amdgcn_perm)
  return __builtin_amdgcn_perm(hi, lo, 0x07060302u);
#else
  return (hi & 0xffff0000u) | (lo >> 16);
#endif
}

// async global->LDS, 16 B per lane; lds dest = base + lane*16 (wave-uniform base)
__device__ __forceinline__ void stage16(const unsigned short* gp, unsigned short* lp) {
#if __has_builtin(__builtin_amdgcn_global_load_lds)
  __builtin_amdgcn_global_load_lds((const __attribute__((address_space(1))) void*)gp,
                                   (__attribute__((address_space(3))) void*)lp, 16, 0, 0);
#else
  *(s16x8*)(lp + (threadIdx.x & 63) * 8) = *(const s16x8*)gp;
#endif
}

// ---------- fused cast fp32 -> bf16 (x, W_qkv, W_out in one launch) ----------
#define N4_X  (TOKENS * DIM / 4)
#define N4_WQ (3 * DIM * DIM / 4)
#define N4_WO (DIM * DIM / 4)
__global__ __launch_bounds__(256) void mhsa_cast_all(const float* __restrict__ x,
    const float* __restrict__ wq, const float* __restrict__ wo,
    unsigned short* __restrict__ xb, unsigned short* __restrict__ wqb,
    unsigned short* __restrict__ wob) {
  int i = blockIdx.x * 256 + threadIdx.x;
  const float* src; unsigned short* dst; int off;
  if (i < N4_X)              { src = x;  dst = xb;  off = i; }
  else if (i < N4_X + N4_WQ) { src = wq; dst = wqb; off = i - N4_X; }
  else                       { src = wo; dst = wob; off = i - (N4_X + N4_WQ); }
  float4v f = ((const float4v*)src)[off];
  u16x4 o;
  o.x = f2bf(f.x); o.y = f2bf(f.y); o.z = f2bf(f.z); o.w = f2bf(f.w);
  ((u16x4*)dst)[off] = o;
}

// ================= GEMM core v3 (unchanged) =================
// BK=32, dbuf, 1 barrier/iter, XOR-swizzled 16B chunks, 3 blocks/CU.

// ---------- QKV GEMM (operand-swapped): C^T layout, packed epilogue ----------
__global__ __launch_bounds__(256, 3) void mhsa_gemm_qkv(const unsigned short* __restrict__ A,
    const unsigned short* __restrict__ Bw, const float* __restrict__ bias,
    unsigned short* __restrict__ qws, unsigned short* __restrict__ kws,
    unsigned short* __restrict__ vws) {
  __shared__ unsigned short As[2][128 * 32];
  __shared__ unsigned short Bs[2][128 * 32];
  const int t = threadIdx.x;
  const int w = t >> 6, l = t & 63;
  const int wm = w >> 1, wn = w & 1;
  const int rowBase = blockIdx.y * 128;   // tokens
  const int colBase = blockIdx.x * 128;   // e
  const int fr = l & 15, q4 = l >> 4, ln = l & 15;
  const int srow = l >> 2;                       // staging row within slab
  const int scol = ((l & 3) ^ (srow & 3)) * 8;   // swizzled global column

  f32x4 zero = {0.f, 0.f, 0.f, 0.f};
  f32x4 acc[4][4];   // [a=e-tile][b=token-tile]
  #pragma unroll
  for (int a = 0; a < 4; ++a)
    #pragma unroll
    for (int b = 0; b < 4; ++b) acc[a][b] = zero;

  #pragma unroll
  for (int it = 0; it < 2; ++it) {
    const int c = w * 2 + it;
    stage16(A  + (size_t)(rowBase + c * 16 + srow) * DIM + scol, &As[0][c * 512]);
    stage16(Bw + (size_t)(colBase + c * 16 + srow) * DIM + scol, &Bs[0][c * 512]);
  }
  __syncthreads();

  for (int kt = 0; kt < DIM / 32; ++kt) {
    const int cur = kt & 1, nxt = cur ^ 1;
    if (kt + 1 < DIM / 32) {
      const int k1 = (kt + 1) * 32;
      #pragma unroll
      for (int it = 0; it < 2; ++it) {
        const int c = w * 2 + it;
        stage16(A  + (size_t)(rowBase + c * 16 + srow) * DIM + k1 + scol, &As[nxt][c * 512]);
        stage16(Bw + (size_t)(colBase + c * 16 + srow) * DIM + k1 + scol, &Bs[nxt][c * 512]);
      }
    }
    s16x8 xf[4], wf[4];
    #pragma unroll
    for (int b = 0; b < 4; ++b)
      xf[b] = *(const s16x8*)&As[cur][(wm * 64 + b * 16 + fr) * 32 + ((q4 ^ (fr & 3)) * 8)];
    #pragma unroll
    for (int a = 0; a < 4; ++a)
      wf[a] = *(const s16x8*)&Bs[cur][(wn * 64 + a * 16 + fr) * 32 + ((q4 ^ (fr & 3)) * 8)];
    #pragma unroll
    for (int a = 0; a < 4; ++a)
      #pragma unroll
      for (int b = 0; b < 4; ++b)
        acc[a][b] = __builtin_amdgcn_mfma_f32_16x16x32_bf16(wf[a], xf[b], acc[a][b], 0, 0, 0);
    __syncthreads();
  }

  const int which = colBase >> 10;   // 0=Q 1=K 2=V (block never straddles)
  const float sc = (which == 0) ? QSCALE : 1.0f;
  unsigned short* dst = (which == 0) ? qws : ((which == 1) ? kws : vws);

  #pragma unroll
  for (int a = 0; a < 4; ++a) {
    const int e0 = colBase + wn * 64 + a * 16 + q4 * 4;  // 4-aligned, 4 consecutive e
    const float4v bs4 = *(const float4v*)&bias[e0];
    const int rr0 = e0 & 1023;
    const int h = rr0 >> 6, d0 = rr0 & 63;               // d0..d0+3 within one head
    #pragma unroll
    for (int b = 0; b < 4; ++b) {
      const int tok = rowBase + wm * 64 + b * 16 + ln;
      const int bb = tok >> 11, n = tok & 2047;
      if (which != 2) {
        u16x4 pk;
        #pragma unroll
        for (int r = 0; r < 4; ++r) pk[r] = f2bf((acc[a][b][r] + bs4[r]) * sc);
        *(u16x4*)&dst[(((size_t)(bb * HEADS + h)) * SEQ + n) * HD + d0] = pk;
      } else {
        #pragma unroll
        for (int r = 0; r < 4; ++r)
          dst[(((size_t)(bb * HEADS + h)) * HD + d0 + r) * SEQ + n] =
              f2bf(acc[a][b][r] + bs4[r]);
      }
    }
  }
}

// ---------- Output GEMM (operand-swapped): 64x128 tiles, float4 epilogue ----------
__global__ __launch_bounds__(256, 3) void mhsa_gemm_out(const unsigned short* __restrict__ A,
    const unsigned short* __restrict__ Bw, const float* __restrict__ bias,
    float* __restrict__ out) {
  __shared__ unsigned short As[2][64 * 32];
  __shared__ unsigned short Bs[2][128 * 32];
  const int t = threadIdx.x;
  const int w = t >> 6, l = t & 63;
  const int wm = w >> 1, wn = w & 1;
  const int rowBase = blockIdx.y * 64;    // tokens (64-row tiles -> 512 blocks)
  const int colBase = blockIdx.x * 128;   // e
  const int fr = l & 15, q4 = l >> 4, ln = l & 15;
  const int srow = l >> 2;
  const int scol = ((l & 3) ^ (srow & 3)) * 8;

  f32x4 zero = {0.f, 0.f, 0.f, 0.f};
  f32x4 acc[4][2];   // [a=e-tile][b=token-tile]
  #pragma unroll
  for (int a = 0; a < 4; ++a)
    #pragma unroll
    for (int b = 0; b < 2; ++b) acc[a][b] = zero;

  #pragma unroll
  for (int it = 0; it < 3; ++it) {
    const int s = w * 3 + it;
    if (s < 4) stage16(A  + (size_t)(rowBase + s * 16 + srow) * DIM + scol, &As[0][s * 512]);
    else       stage16(Bw + (size_t)(colBase + (s - 4) * 16 + srow) * DIM + scol, &Bs[0][(s - 4) * 512]);
  }
  __syncthreads();

  for (int kt = 0; kt < DIM / 32; ++kt) {
    const int cur = kt & 1, nxt = cur ^ 1;
    if (kt + 1 < DIM / 32) {
      const int k1 = (kt + 1) * 32;
      #pragma unroll
      for (int it = 0; it < 3; ++it) {
        const int s = w * 3 + it;
        if (s < 4) stage16(A  + (size_t)(rowBase + s * 16 + srow) * DIM + k1 + scol, &As[nxt][s * 512]);
        else       stage16(Bw + (size_t)(colBase + (s - 4) * 16 + srow) * DIM + k1 + scol, &Bs[nxt][(s - 4) * 512]);
      }
    }
    s16x8 xf[2], wf[4];
    #pragma unroll
    for (int b = 0; b < 2; ++b)
      xf[b] = *(const s16x8*)&As[cur][(wm * 32 + b * 16 + fr) * 32 + ((q4 ^ (fr & 3)) * 8)];
    #pragma unroll
    for (int a = 0; a < 4; ++a)
      wf[a] = *(const s16x8*)&Bs[cur][(wn * 64 + a * 16 + fr) * 32 + ((q4 ^ (fr & 3)) * 8)];
    #pragma unroll
    for (int a = 0; a < 4; ++a)
      #pragma unroll
      for (int b = 0; b < 2; ++b)
        acc[a][b] = __builtin_amdgcn_mfma_f32_16x16x32_bf16(wf[a], xf[b], acc[a][b], 0, 0, 0);
    __syncthreads();
  }

  #pragma unroll
  for (int a = 0; a < 4; ++a) {
    const int e0 = colBase + wn * 64 + a * 16 + q4 * 4;
    const float4v bs4 = *(const float4v*)&bias[e0];
    #pragma unroll
    for (int b = 0; b < 2; ++b) {
      const int tok = rowBase + wm * 32 + b * 16 + ln;
      float4v v;
      #pragma unroll
      for (int r = 0; r < 4; ++r) v[r] = acc[a][b][r] + bs4[r];
      *(float4v*)&out[(size_t)tok * DIM + e0] = v;
    }
  }
}

// ---------- Flash attention v11: 32x32 MFMA, P in-register; FIXED permlane mapping ----------
// 256 threads (4 waves x 32 q-rows each). Swapped QK^T: St = mfma_32x32x16(A=K, B=Q)
// -> D col (lane&31) = q, rows = kv: kv = (r&3)+8(r>>2)+4*hi (+32*tile).
// After exp/pack, lane (ln,hi) holds cp[m]: m in {0,1}: kv 4hi+{0..3}; {2,3}: 8+4hi+..;
// {4,5}: 16+4hi+..; {6,7}: 24+4hi+.. (cp1: +32). Target pa[ks] dwords = kv 16ks+8hi+
// {0,1|2,3|4,5|6,7}. v_permlane32_swap_b32(vdst,vsrc) exchanges vdst.hi-lanes with
// vsrc.lo-lanes => swap(cp[t+0],cp[t+2]) + swap(cp[t+1],cp[t+3]), t=4*(ks&1), and
// pa = {cp[t+0]',cp[t+1]',cp[t+2]',cp[t+3]'}  (v10 had operands AND dwords scrambled).
// Verified on all (hi, dword) quadrants for pa[0]/pa[1] against A-operand layout
// A[m=lane&31][k=8*(lane>>5)+j].
__global__ __launch_bounds__(256, 2) void mhsa_attn(const unsigned short* __restrict__ q,
    const unsigned short* __restrict__ k, const unsigned short* __restrict__ vt,
    unsigned short* __restrict__ o) {
  __shared__ unsigned short Qs[4][32 * 64];   // per-wave Q staging (swizzled chunks)
  __shared__ unsigned short Ks[2][64 * 64];   // dbuf K tile [kv][d]
  __shared__ unsigned short Vs[2][64 * 64];   // dbuf V^T tile [d][kv]
  const int t = threadIdx.x, w = t >> 6, l = t & 63;
  const int ln = l & 31, hi = l >> 5;
  const int bh = blockIdx.y, q0 = blockIdx.x * 128;
  const unsigned short* qb  = q  + (size_t)bh * SEQ * HD;
  const unsigned short* kb  = k  + (size_t)bh * SEQ * HD;
  const unsigned short* vtb = vt + (size_t)bh * HD * SEQ;

  const int srow = l >> 3;
  const int scol = ((l & 7) ^ srow) * 8;
  const int swz = ln & 7;   // row-swizzle key for frag reads (row&7 == ln&7 everywhere)

  // bf16 1.0 x8 for the row-sum MFMA B operand
  const s16x8 vones = {(short)0x3F80, (short)0x3F80, (short)0x3F80, (short)0x3F80,
                       (short)0x3F80, (short)0x3F80, (short)0x3F80, (short)0x3F80};

  // prologue staging: Q (wave-local region), K_0, V_0
  #pragma unroll
  for (int it = 0; it < 4; ++it)
    stage16(qb + (size_t)(q0 + w * 32 + it * 8 + srow) * HD + scol, &Qs[w][it * 512]);
  #pragma unroll
  for (int it = 0; it < 2; ++it) {
    const int c = w + it * 4;
    stage16(kb  + (size_t)(c * 8 + srow) * HD + scol,  &Ks[0][c * 512]);
    stage16(vtb + (size_t)(c * 8 + srow) * SEQ + scol, &Vs[0][c * 512]);
  }
  __syncthreads();

  // hoist Q B-fragments: aq[kc] = Q[q=ln][d = 16kc + 8hi + 0..7]
  s16x8 aq[4];
  #pragma unroll
  for (int kc = 0; kc < 4; ++kc)
    aq[kc] = *(const s16x8*)&Qs[w][ln * 64 + (((2 * kc + hi) ^ swz) * 8)];

  f32x16 z16;
  #pragma unroll
  for (int i = 0; i < 16; ++i) z16[i] = 0.f;
  f32x16 accO0 = z16, accO1 = z16, accS = z16;

  const int NT = SEQ / 64;   // 32
  for (int jt = 0; jt < NT; ++jt) {
    const int cur = jt & 1, nxt = cur ^ 1;
    // stage K_{jt+1}, V_{jt+1} into slot nxt (its prior reads drained at last barrier)
    if (jt + 1 < NT) {
      const int j1 = (jt + 1) * 64;
      #pragma unroll
      for (int it = 0; it < 2; ++it) {
        const int c = w + it * 4;
        stage16(kb  + (size_t)(j1 + c * 8 + srow) * HD + scol,  &Ks[nxt][c * 512]);
        stage16(vtb + (size_t)(c * 8 + srow) * SEQ + j1 + scol, &Vs[nxt][c * 512]);
      }
    }

    // ---- S = K x Q (swapped): St0 = kv 0..31, St1 = kv 32..63 ----
    f32x16 St0 = z16, St1 = z16;
    __builtin_amdgcn_s_setprio(1);
    #pragma unroll
    for (int kc = 0; kc < 4; ++kc) {
      s16x8 ak0 = *(const s16x8*)&Ks[cur][ln * 64 + (((2 * kc + hi) ^ swz) * 8)];
      s16x8 ak1 = *(const s16x8*)&Ks[cur][(32 + ln) * 64 + (((2 * kc + hi) ^ swz) * 8)];
      St0 = __builtin_amdgcn_mfma_f32_32x32x16_bf16(ak0, aq[kc], St0, 0, 0, 0);
      St1 = __builtin_amdgcn_mfma_f32_32x32x16_bf16(ak1, aq[kc], St1, 0, 0, 0);
    }
    __builtin_amdgcn_s_setprio(0);

    // ---- exp2 -> bf16 pack: cp[tile][m] holds kv'-pair {2m-th, 2m+1-th} regs ----
    uint32_t cp0[8], cp1[8];
    #pragma unroll
    for (int m = 0; m < 8; ++m) {
      cp0[m] = pack_bf16_trunc(__float_as_uint(fast_exp2(St0[2 * m])),
                               __float_as_uint(fast_exp2(St0[2 * m + 1])));
      cp1[m] = pack_bf16_trunc(__float_as_uint(fast_exp2(St1[2 * m])),
                               __float_as_uint(fast_exp2(St1[2 * m + 1])));
    }

    // ---- cross-half redistribution (FIXED): pa[ks] = P[q=ln][kv=16ks+8hi+0..7] ----
    // swap(cp[t+0], cp[t+2]) and swap(cp[t+1], cp[t+3]), t = 4*(ks&1):
    //   cp[t+0]'.lo = own kv(a,a+1)      cp[t+0]'.hi = partner cp[t+2] = kv(a+8,..)
    //   cp[t+2]'.lo = partner cp[t+0] = kv(a+4,..)   cp[t+2]'.hi = own kv(a+12,..)
    // => pa dwords {cp[t+0]', cp[t+1]', cp[t+2]', cp[t+3]'} give kv = base+8hi+0..7.
    s16x8 pa[4];
    #pragma unroll
    for (int ks = 0; ks < 4; ++ks) {
      const int tb = 4 * (ks & 1);
      uint32_t d0 = (ks < 2) ? cp0[tb + 0] : cp1[tb + 0];
      uint32_t d1 = (ks < 2) ? cp0[tb + 1] : cp1[tb + 1];
      uint32_t d2 = (ks < 2) ? cp0[tb + 2] : cp1[tb + 2];
      uint32_t d3 = (ks < 2) ? cp0[tb + 3] : cp1[tb + 3];
      asm("v_permlane32_swap_b32 %0, %1" : "+v"(d0), "+v"(d2));
      asm("v_permlane32_swap_b32 %0, %1" : "+v"(d1), "+v"(d3));
      u32x4 pd; pd.x = d0; pd.y = d1; pd.z = d2; pd.w = d3;
      pa[ks] = __builtin_bit_cast(s16x8, pd);
    }

    // ---- rowsum + PV ----
    __builtin_amdgcn_s_setprio(1);
    #pragma unroll
    for (int ks = 0; ks < 4; ++ks)
      accS = __builtin_amdgcn_mfma_f32_32x32x16_bf16(pa[ks], vones, accS, 0, 0, 0);
    #pragma unroll
    for (int ks = 0; ks < 4; ++ks) {
      s16x8 bv0 = *(const s16x8*)&Vs[cur][ln * 64 + (((2 * ks + hi) ^ swz) * 8)];
      s16x8 bv1 = *(const s16x8*)&Vs[cur][(32 + ln) * 64 + (((2 * ks + hi) ^ swz) * 8)];
      accO0 = __builtin_amdgcn_mfma_f32_32x32x16_bf16(pa[ks], bv0, accO0, 0, 0, 0);
      accO1 = __builtin_amdgcn_mfma_f32_32x32x16_bf16(pa[ks], bv1, accO1, 0, 0, 0);
    }
    __builtin_amdgcn_s_setprio(0);

    __syncthreads();   // publishes nxt staging; drains cur-slot reads before reuse
  }

  // epilogue: accS rows = q with the SAME reg map as accO -> normalize + store
  const int b = bh >> 4, h = bh & 15;
  #pragma unroll
  for (int r = 0; r < 16; ++r) {
    const int ql = (r & 3) + 8 * (r >> 2) + 4 * hi;
    const float inv = 1.f / accS[r];
    const int row = q0 + w * 32 + ql;
    o[((size_t)(b * SEQ + row)) * DIM + h * HD + ln]      = f2bf(accO0[r] * inv);
    o[((size_t)(b * SEQ + row)) * DIM + h * HD + 32 + ln] = f2bf(accO1[r] * inv);
  }
}

// ---------- launch ----------
extern "C" void kernel_launch(void* const* d_in, const int* in_sizes, int n_in,
                              void* d_out, int out_size, void* d_ws, size_t ws_size,
                              hipStream_t stream) {
  const float* x     = (const float*)d_in[0];   // [2,2048,1024]
  const float* Wqkv  = (const float*)d_in[1];   // [3072,1024]
  const float* bqkv  = (const float*)d_in[2];   // [3072]
  const float* Wout  = (const float*)d_in[3];   // [1024,1024]
  const float* bout  = (const float*)d_in[4];   // [1024]
  float* out = (float*)d_out;

  unsigned short* ws = (unsigned short*)d_ws;
  unsigned short* x_bf    = ws;
  unsigned short* wqkv_bf = x_bf    + (size_t)TOKENS * DIM;
  unsigned short* wout_bf = wqkv_bf + (size_t)3 * DIM * DIM;
  unsigned short* q_ws    = wout_bf + (size_t)DIM * DIM;
  unsigned short* k_ws    = q_ws    + (size_t)TOKENS * DIM;
  unsigned short* v_ws    = k_ws    + (size_t)TOKENS * DIM;    // transposed [bh][d][n]
  unsigned short* ao_ws   = v_ws    + (size_t)TOKENS * DIM;

  // fused cast (one launch)
  {
    const int n4 = N4_X + N4_WQ + N4_WO;   // 2,097,152 -> 8192 blocks
    mhsa_cast_all<<<n4 / 256, 256, 0, stream>>>(x, Wqkv, Wout, x_bf, wqkv_bf, wout_bf);
  }

  // QKV projection + scatter (V transposed, Q pre-scaled)
  {
    dim3 grid(3 * DIM / 128, TOKENS / 128);   // (24, 32) = 768 blocks = 3/CU, one round
    mhsa_gemm_qkv<<<grid, 256, 0, stream>>>(x_bf, wqkv_bf, bqkv, q_ws, k_ws, v_ws);
  }

  // fused attention
  {
    dim3 grid(SEQ / 128, BATCH * HEADS);      // (16, 32), 256 threads
    mhsa_attn<<<grid, 256, 0, stream>>>(q_ws, k_ws, v_ws, ao_ws);
  }

  // output projection
  {
    dim3 grid(DIM / 128, TOKENS / 64);        // (8, 64) = 512 blocks
    mhsa_gemm_out<<<grid, 256, 0, stream>>>(ao_ws, wout_bf, bout, out);
  }
}